// Round 1
// baseline (1353.401 us; speedup 1.0000x reference)
//
#include <hip/hip_runtime.h>

// Problem constants
#define BB 2048
#define FF 64
#define DD 512
#define AA 512
#define HH 8
#define HD 64
#define MM (BB*FF)   // 131072

typedef unsigned short ushort_t;
typedef __bf16 bf16x8_t __attribute__((ext_vector_type(8)));
typedef float f32x4_t __attribute__((ext_vector_type(4)));

__device__ __forceinline__ ushort_t f2b(float f){
  unsigned x = __float_as_uint(f);
  return (ushort_t)((x + 0x7fffu + ((x>>16)&1u)) >> 16);   // RNE f32->bf16
}
__device__ __forceinline__ float b2f(ushort_t u){
  return __uint_as_float(((unsigned)u)<<16);
}
__device__ __forceinline__ bf16x8_t ld_frag(const ushort_t* p){
  union { uint4 u; bf16x8_t b; } t;
  t.u = *(const uint4*)p;
  return t.b;
}

// ---------------------------------------------------------------------------
// Kernel 0: transpose + convert weights f32[512][512] -> bf16 WT[n][k]
// grid (16,16,3), block 256
// ---------------------------------------------------------------------------
__global__ __launch_bounds__(256) void prep_w(const float* __restrict__ Wq,
                                              const float* __restrict__ Wk,
                                              const float* __restrict__ Wv,
                                              ushort_t* __restrict__ WT){
  const int mat = blockIdx.z;
  const float* W = (mat==0) ? Wq : ((mat==1) ? Wk : Wv);
  ushort_t* o = WT + (size_t)mat*DD*AA;
  __shared__ float tile[32][33];
  const int t = threadIdx.x;
  const int k0 = blockIdx.x*32, n0 = blockIdx.y*32;
#pragma unroll
  for(int it=0; it<4; ++it){
    int idx = t + it*256; int r = idx>>5, c = idx&31;
    tile[r][c] = W[(size_t)(k0+r)*AA + n0 + c];
  }
  __syncthreads();
#pragma unroll
  for(int it=0; it<4; ++it){
    int idx = t + it*256; int r = idx>>5, c = idx&31;
    o[(size_t)(n0+r)*DD + k0 + c] = f2b(tile[c][r]);
  }
}

// ---------------------------------------------------------------------------
// Kernel 1: QKV GEMM.  C[m,n] = A[m,:] @ W[:,n]  (no bias for Q,K; +bv for V)
// A = query/key/value f32 [131072 x 512]; W via WT bf16 [n][k].
// Q,K stored row-major bf16 [m][n].  V stored TRANSPOSED per batch:
// Vt[b][d][f]  (b = m>>6, f = m&63, d = n)  so attention's PV step can read
// V fragments k-inner with coalesced 16B loads.
// grid (12, 1024): x = mat*4 + nb;  block 256 (4 waves, 2x2 of 64x64)
// ---------------------------------------------------------------------------
__global__ __launch_bounds__(256) void gemm_qkv(const float* __restrict__ q,
                                                const float* __restrict__ k,
                                                const float* __restrict__ v,
                                                const ushort_t* __restrict__ WTall,
                                                const float* __restrict__ bv,
                                                ushort_t* __restrict__ Call){
  const int bx = blockIdx.x;
  const int mat = bx >> 2;
  const int nb  = bx & 3;
  const float* Ain = (mat==0) ? q : ((mat==1) ? k : v);
  const ushort_t* WT = WTall + (size_t)mat*DD*AA;
  ushort_t* Cout = Call + (size_t)mat*MM*AA;
  const int m0 = blockIdx.y * 128;
  const int n0 = nb * 128;

  __shared__ __align__(16) ushort_t As[128][40];
  __shared__ __align__(16) ushort_t Bs[128][40];

  const int t = threadIdx.x;
  const int wid = t >> 6, lane = t & 63;
  const int wm = wid >> 1, wn = wid & 1;
  const int lm = lane & 15, lk = lane >> 4;

  f32x4_t acc[4][4];
#pragma unroll
  for(int a=0;a<4;++a)
#pragma unroll
    for(int bq=0;bq<4;++bq) acc[a][bq] = (f32x4_t){0.f,0.f,0.f,0.f};

  for(int k0=0; k0<DD; k0+=32){
    __syncthreads();
    // stage A tile 128x32 f32 -> bf16 LDS
#pragma unroll
    for(int it=0; it<4; ++it){
      int idx = t + it*256;
      int r = idx >> 3;
      int c4 = (idx & 7) * 4;
      const float4 f = *(const float4*)(Ain + (size_t)(m0+r)*DD + k0 + c4);
      uint2 u;
      u.x = (unsigned)f2b(f.x) | ((unsigned)f2b(f.y) << 16);
      u.y = (unsigned)f2b(f.z) | ((unsigned)f2b(f.w) << 16);
      *(uint2*)&As[r][c4] = u;
    }
    // stage B tile (WT rows n0..n0+127, cols k0..k0+31) bf16 -> LDS
#pragma unroll
    for(int it=0; it<2; ++it){
      int idx = t + it*256;
      int r = idx >> 2;
      int c8 = (idx & 3) * 8;
      uint4 w = *(const uint4*)(WT + (size_t)(n0+r)*DD + k0 + c8);
      *(uint4*)&Bs[r][c8] = w;
    }
    __syncthreads();

    bf16x8_t af[4], bfv[4];
#pragma unroll
    for(int mt=0; mt<4; ++mt) af[mt]  = ld_frag(&As[wm*64 + mt*16 + lm][lk*8]);
#pragma unroll
    for(int nt=0; nt<4; ++nt) bfv[nt] = ld_frag(&Bs[wn*64 + nt*16 + lm][lk*8]);
#pragma unroll
    for(int mt=0; mt<4; ++mt)
#pragma unroll
      for(int nt=0; nt<4; ++nt)
        acc[mt][nt] = __builtin_amdgcn_mfma_f32_16x16x32_bf16(af[mt], bfv[nt], acc[mt][nt], 0, 0, 0);
  }

  // epilogue
  if(mat == 2){
    // V: +bias, store transposed per batch: Vt[b][d][f], f contiguous.
    // rows handled by this lane: m = m0 + wm*64 + (mt*16 + lk*4 + reg)
    //   -> b = m0/64 + wm (constant), f = mt*16 + lk*4 + reg (0..63)
    const int bb = (m0 >> 6) + wm;
#pragma unroll
    for(int nt=0; nt<4; ++nt){
      const int col = n0 + wn*64 + nt*16 + lm;      // d
      const float bias = bv[col];
      ushort_t* vrow = Cout + ((size_t)bb*AA + col)*FF;
#pragma unroll
      for(int mt=0; mt<4; ++mt){
        const int f0 = mt*16 + lk*4;
        uint2 u;
        u.x = (unsigned)f2b(acc[mt][nt][0] + bias) | ((unsigned)f2b(acc[mt][nt][1] + bias) << 16);
        u.y = (unsigned)f2b(acc[mt][nt][2] + bias) | ((unsigned)f2b(acc[mt][nt][3] + bias) << 16);
        *(uint2*)(vrow + f0) = u;
      }
    }
  } else {
    // Q,K: bf16 row-major store
#pragma unroll
    for(int nt=0; nt<4; ++nt){
      const int col = n0 + wn*64 + nt*16 + lm;
#pragma unroll
      for(int mt=0; mt<4; ++mt){
#pragma unroll
        for(int reg=0; reg<4; ++reg){
          const int row = m0 + wm*64 + mt*16 + lk*4 + reg;
          Cout[(size_t)row*AA + col] = f2b(acc[mt][nt][reg]);
        }
      }
    }
  }
}

// ---------------------------------------------------------------------------
// Kernel 2: per-batch attention. grid 2048, block 256 (4 waves, 2 heads each)
// S = Q@K^T - u[k];  P = softmax_k(S);  out = P@V + Vsum + query, relu
// V arrives TRANSPOSED: Vt[b][d][f]
// ---------------------------------------------------------------------------
__global__ __launch_bounds__(256) void attn(const ushort_t* __restrict__ Qws,
                                            const ushort_t* __restrict__ Kws,
                                            const ushort_t* __restrict__ Vt,
                                            const float* __restrict__ query,
                                            float* __restrict__ out){
  const int b = blockIdx.x;
  const int t = threadIdx.x;
  __shared__ float mu[DD];
  __shared__ float vsum[DD];
  __shared__ float uu[HH][FF];
  __shared__ __align__(16) ushort_t P[4][64][72];

  const ushort_t* Qb = Qws + (size_t)b*FF*AA;
  const ushort_t* Kb = Kws + (size_t)b*FF*AA;
  const ushort_t* Vb = Vt  + (size_t)b*AA*FF;   // [d][f]

  // column means of Q (for centering)
  {
    float s0=0.f, s1=0.f;
#pragma unroll 8
    for(int f=0; f<FF; ++f){
      const ushort_t* qr = Qb + f*AA;
      s0 += b2f(qr[t]);     s1 += b2f(qr[t+256]);
    }
    mu[t]     = s0 * (1.f/64.f);
    mu[t+256] = s1 * (1.f/64.f);
  }
  // column sums of V == row sums of Vt (vectorized contiguous reads)
  {
#pragma unroll
    for(int it=0; it<2; ++it){
      const int d = t + it*256;
      const ushort_t* vr = Vb + (size_t)d*FF;
      float a = 0.f;
#pragma unroll
      for(int c=0; c<8; ++c){
        union { uint4 u; ushort_t s[8]; } w;
        w.u = *(const uint4*)(vr + c*8);
#pragma unroll
        for(int j=0; j<8; ++j) a += b2f(w.s[j]);
      }
      vsum[d] = a;
    }
  }
  __syncthreads();

  // u[h][k] = mu_h . K_h[k]
#pragma unroll
  for(int it=0; it<2; ++it){
    int idx = t + it*256;
    int h = idx >> 6, kk = idx & 63;
    const ushort_t* Kr = Kb + kk*AA + h*HD;
    float a = 0.f;
#pragma unroll
    for(int c=0; c<8; ++c){
      union { uint4 u; ushort_t s[8]; } w;
      w.u = *(const uint4*)(Kr + c*8);
#pragma unroll
      for(int j=0; j<8; ++j) a += mu[h*HD + c*8 + j] * b2f(w.s[j]);
    }
    uu[h][kk] = a;
  }
  __syncthreads();

  const int wave = t >> 6, lane = t & 63;
  const int lm = lane & 15, lk = lane >> 4;

  for(int hh=0; hh<2; ++hh){
    const int h = wave*2 + hh;

    // ---- scores S = Q_h @ K_h^T  (64x64, K-dim 64) ----
    f32x4_t acc[4][4];
#pragma unroll
    for(int a=0;a<4;++a)
#pragma unroll
      for(int bq=0;bq<4;++bq) acc[a][bq] = (f32x4_t){0.f,0.f,0.f,0.f};
#pragma unroll
    for(int ks=0; ks<2; ++ks){
      bf16x8_t af[4], bfv[4];
#pragma unroll
      for(int mt=0; mt<4; ++mt)
        af[mt]  = ld_frag(Qb + (size_t)(mt*16+lm)*AA + h*HD + ks*32 + lk*8);
#pragma unroll
      for(int nt=0; nt<4; ++nt)
        bfv[nt] = ld_frag(Kb + (size_t)(nt*16+lm)*AA + h*HD + ks*32 + lk*8);
#pragma unroll
      for(int mt=0; mt<4; ++mt)
#pragma unroll
        for(int nt=0; nt<4; ++nt)
          acc[mt][nt] = __builtin_amdgcn_mfma_f32_16x16x32_bf16(af[mt], bfv[nt], acc[mt][nt], 0, 0, 0);
    }

    // ---- subtract u, row softmax (row = mt*16+lk*4+reg; col = nt*16+lm) ----
    float uval[4];
#pragma unroll
    for(int nt=0; nt<4; ++nt) uval[nt] = uu[h][nt*16 + lm];

#pragma unroll
    for(int mt=0; mt<4; ++mt){
#pragma unroll
      for(int reg=0; reg<4; ++reg){
        float x0 = acc[mt][0][reg] - uval[0];
        float x1 = acc[mt][1][reg] - uval[1];
        float x2 = acc[mt][2][reg] - uval[2];
        float x3 = acc[mt][3][reg] - uval[3];
        float m = fmaxf(fmaxf(x0,x1), fmaxf(x2,x3));
        m = fmaxf(m, __shfl_xor(m, 1));
        m = fmaxf(m, __shfl_xor(m, 2));
        m = fmaxf(m, __shfl_xor(m, 4));
        m = fmaxf(m, __shfl_xor(m, 8));
        float e0 = __expf(x0-m), e1 = __expf(x1-m), e2 = __expf(x2-m), e3 = __expf(x3-m);
        float s = e0+e1+e2+e3;
        s += __shfl_xor(s, 1);
        s += __shfl_xor(s, 2);
        s += __shfl_xor(s, 4);
        s += __shfl_xor(s, 8);
        const float inv = 1.f / s;
        const int row = mt*16 + lk*4 + reg;
        P[wave][row][0*16 + lm] = f2b(e0*inv);
        P[wave][row][1*16 + lm] = f2b(e1*inv);
        P[wave][row][2*16 + lm] = f2b(e2*inv);
        P[wave][row][3*16 + lm] = f2b(e3*inv);
      }
    }

    // ---- out_h = P @ V_h  (64x64) ----
    // B-operand = Vt rows (d-major, f-contiguous): coalesced 16B loads.
    f32x4_t acc2[4][4];
#pragma unroll
    for(int a=0;a<4;++a)
#pragma unroll
      for(int bq=0;bq<4;++bq) acc2[a][bq] = (f32x4_t){0.f,0.f,0.f,0.f};
#pragma unroll
    for(int ks=0; ks<2; ++ks){
      bf16x8_t pf[4], vf[4];
#pragma unroll
      for(int mt=0; mt<4; ++mt)
        pf[mt] = ld_frag(&P[wave][mt*16 + lm][ks*32 + lk*8]);
#pragma unroll
      for(int nt=0; nt<4; ++nt)
        vf[nt] = ld_frag(Vb + (size_t)(h*HD + nt*16 + lm)*FF + ks*32 + lk*8);
#pragma unroll
      for(int mt=0; mt<4; ++mt)
#pragma unroll
        for(int nt=0; nt<4; ++nt)
          acc2[mt][nt] = __builtin_amdgcn_mfma_f32_16x16x32_bf16(pf[mt], vf[nt], acc2[mt][nt], 0, 0, 0);
    }

    // ---- epilogue: + Vsum + residual, relu, store f32 ----
#pragma unroll
    for(int mt=0; mt<4; ++mt){
#pragma unroll
      for(int nt=0; nt<4; ++nt){
        const int dd = h*HD + nt*16 + lm;
#pragma unroll
        for(int reg=0; reg<4; ++reg){
          const int qrow = mt*16 + lk*4 + reg;
          const size_t gi = ((size_t)b*FF + qrow)*DD + dd;
          float val = acc2[mt][nt][reg] + vsum[dd] + query[gi];
          out[gi] = fmaxf(val, 0.f);
        }
      }
    }
  }
}

// ---------------------------------------------------------------------------
extern "C" void kernel_launch(void* const* d_in, const int* in_sizes, int n_in,
                              void* d_out, int out_size, void* d_ws, size_t ws_size,
                              hipStream_t stream){
  const float* query = (const float*)d_in[0];
  const float* key   = (const float*)d_in[1];
  const float* value = (const float*)d_in[2];
  const float* Wq    = (const float*)d_in[3];
  const float* Wk    = (const float*)d_in[5];
  const float* Wv    = (const float*)d_in[7];
  const float* bv    = (const float*)d_in[8];
  // Wk2/bk2/bq/bk unused: unary softmax over size-1 axis == 1, and bq/bk are
  // softmax-invariant after centering.

  ushort_t* WT  = (ushort_t*)d_ws;                              // 3 x 512x512 bf16
  ushort_t* QKV = (ushort_t*)((char*)d_ws + (size_t)(1<<21));   // Q,K row-major + Vt
  float* out = (float*)d_out;

  prep_w<<<dim3(16,16,3), 256, 0, stream>>>(Wq, Wk, Wv, WT);
  gemm_qkv<<<dim3(12,1024), 256, 0, stream>>>(query, key, value, WT, bv, QKV);
  attn<<<2048, 256, 0, stream>>>(QKV,
                                 QKV + (size_t)MM*AA,
                                 QKV + 2*(size_t)MM*AA,
                                 query, out);
}

// Round 2
// 1201.455 us; speedup vs baseline: 1.1265x; 1.1265x over previous
//
#include <hip/hip_runtime.h>
#include <stdint.h>

// Problem constants
#define BB 2048
#define FF 64
#define DD 512
#define AA 512
#define HH 8
#define HD 64
#define MM (BB*FF)   // 131072

typedef unsigned short ushort_t;
typedef __bf16 bf16x8_t __attribute__((ext_vector_type(8)));
typedef float f32x4_t __attribute__((ext_vector_type(4)));

__device__ __forceinline__ ushort_t f2b(float f){
  unsigned x = __float_as_uint(f);
  return (ushort_t)((x + 0x7fffu + ((x>>16)&1u)) >> 16);   // RNE f32->bf16
}
__device__ __forceinline__ float b2f(ushort_t u){
  return __uint_as_float(((unsigned)u)<<16);
}
__device__ __forceinline__ bf16x8_t ld_frag(const ushort_t* p){
  union { uint4 u; bf16x8_t b; } t;
  t.u = *(const uint4*)p;
  return t.b;
}

// async global->LDS DMA, 16B per lane. LDS dest must be linear in lane order.
__device__ __forceinline__ void async16(void* lds, const void* g){
  __builtin_amdgcn_global_load_lds(
      (const __attribute__((address_space(1))) uint32_t*)(uintptr_t)g,
      (__attribute__((address_space(3))) uint32_t*)(uint32_t)(uintptr_t)lds,
      16, 0, 0);
}

// ---------------------------------------------------------------------------
// Kernel 0: transpose + convert weights f32[512][512] -> bf16 WT[n][k]
// grid (16,16,3), block 256
// ---------------------------------------------------------------------------
__global__ __launch_bounds__(256) void prep_w(const float* __restrict__ Wq,
                                              const float* __restrict__ Wk,
                                              const float* __restrict__ Wv,
                                              ushort_t* __restrict__ WT){
  const int mat = blockIdx.z;
  const float* W = (mat==0) ? Wq : ((mat==1) ? Wk : Wv);
  ushort_t* o = WT + (size_t)mat*DD*AA;
  __shared__ float tile[32][33];
  const int t = threadIdx.x;
  const int k0 = blockIdx.x*32, n0 = blockIdx.y*32;
#pragma unroll
  for(int it=0; it<4; ++it){
    int idx = t + it*256; int r = idx>>5, c = idx&31;
    tile[r][c] = W[(size_t)(k0+r)*AA + n0 + c];
  }
  __syncthreads();
#pragma unroll
  for(int it=0; it<4; ++it){
    int idx = t + it*256; int r = idx>>5, c = idx&31;
    o[(size_t)(n0+r)*DD + k0 + c] = f2b(tile[c][r]);
  }
}

// ---------------------------------------------------------------------------
// Kernel 1: QKV GEMM.  C[m,n] = A[m,:] @ W[:,n]
// A f32 [131072 x 512] staged raw (f32) into LDS via global_load_lds with
// XOR-swizzled SOURCE (linear dest, rule #21), converted to bf16 at
// fragment-read with hardware cvt.  B (WT bf16 [n][k]) also via DMA+swizzle.
// BK=64 (8 K-steps), LDS 48KB -> 3 blocks/CU.
// 1D grid 12288, XCD-grouped: the 4 nb blocks sharing an A tile are
// consecutive on one XCD so A's redundant reads hit that XCD's L2.
// Q,K stored row-major bf16 [m][n]; V stored transposed per batch Vt[b][d][f].
// ---------------------------------------------------------------------------
__global__ __launch_bounds__(256) void gemm_qkv(const float* __restrict__ q,
                                                const float* __restrict__ k,
                                                const float* __restrict__ v,
                                                const ushort_t* __restrict__ WTall,
                                                const float* __restrict__ bv,
                                                ushort_t* __restrict__ Call){
  const int bid = blockIdx.x;
  const int xcd = bid & 7;
  const int j   = bid >> 3;          // 0..1535 per XCD
  const int mat = j / 512;
  const int r0  = j % 512;
  const int mb  = xcd*128 + (r0 >> 2);   // 0..1023
  const int nb  = r0 & 3;
  const int m0  = mb * 128;
  const int n0  = nb * 128;

  const float* Ain = (mat==0) ? q : ((mat==1) ? k : v);
  const ushort_t* WT = WTall + (size_t)mat*DD*AA;
  ushort_t* Cout = Call + (size_t)mat*MM*AA;

  // A: 128 rows x 256B (64 f32, 16 chunks of 16B, chunk slot = ch ^ (row&15))
  // B: 128 rows x 128B (64 bf16, 8 chunks of 16B, chunk slot = ch ^ (row&7))
  __shared__ __align__(16) unsigned char smem[49152];
  unsigned char* As = smem;
  unsigned char* Bs = smem + 32768;

  const int t = threadIdx.x;
  const int wid = t >> 6, lane = t & 63;
  const int wm = wid >> 1, wn = wid & 1;
  const int lm = lane & 15, lk = lane >> 4;

  f32x4_t acc[4][4];
#pragma unroll
  for(int a=0;a<4;++a)
#pragma unroll
    for(int bq=0;bq<4;++bq) acc[a][bq] = (f32x4_t){0.f,0.f,0.f,0.f};

  const char* Ab = (const char*)(Ain + (size_t)m0*DD);   // row stride 2048B
  const char* Bb = (const char*)(WT + (size_t)n0*DD);    // row stride 1024B

  for(int k0=0; k0<DD; k0+=64){
    __syncthreads();
    // stage A: 2048 chunks, linear LDS dest, swizzled global source
#pragma unroll
    for(int i=0;i<8;++i){
      const int L  = i*256 + t;
      const int rr = L >> 4, ss = L & 15;
      const int ch = ss ^ (rr & 15);
      async16(As + L*16, Ab + (size_t)rr*2048 + (size_t)k0*4 + ch*16);
    }
    // stage B: 1024 chunks
#pragma unroll
    for(int i=0;i<4;++i){
      const int L  = i*256 + t;
      const int rr = L >> 3, ss = L & 7;
      const int ch = ss ^ (rr & 7);
      async16(Bs + L*16, Bb + (size_t)rr*1024 + (size_t)k0*2 + ch*16);
    }
    __syncthreads();   // compiler emits vmcnt(0) drain before barrier

#pragma unroll
    for(int kk=0; kk<2; ++kk){
      bf16x8_t af[4], bfv[4];
#pragma unroll
      for(int mt=0; mt<4; ++mt){
        const int ra = wm*64 + mt*16 + lm;
        const int c0 = kk*8 + lk*2;
        const f32x4_t a0 = *(const f32x4_t*)(As + ra*256 + ((c0    ) ^ (ra & 15))*16);
        const f32x4_t a1 = *(const f32x4_t*)(As + ra*256 + ((c0 + 1) ^ (ra & 15))*16);
        union { bf16x8_t v; __bf16 e[8]; } u;
        u.e[0]=(__bf16)a0[0]; u.e[1]=(__bf16)a0[1]; u.e[2]=(__bf16)a0[2]; u.e[3]=(__bf16)a0[3];
        u.e[4]=(__bf16)a1[0]; u.e[5]=(__bf16)a1[1]; u.e[6]=(__bf16)a1[2]; u.e[7]=(__bf16)a1[3];
        af[mt] = u.v;
      }
#pragma unroll
      for(int nt=0; nt<4; ++nt){
        const int rb = wn*64 + nt*16 + lm;
        const int ch = kk*4 + lk;
        bfv[nt] = *(const bf16x8_t*)(Bs + rb*128 + ((ch ^ (rb & 7)))*16);
      }
#pragma unroll
      for(int mt=0; mt<4; ++mt)
#pragma unroll
        for(int nt=0; nt<4; ++nt)
          acc[mt][nt] = __builtin_amdgcn_mfma_f32_16x16x32_bf16(af[mt], bfv[nt], acc[mt][nt], 0, 0, 0);
    }
  }

  // epilogue
  if(mat == 2){
    // V: +bias, store transposed per batch: Vt[b][d][f], f contiguous.
    const int bb = (m0 >> 6) + wm;
#pragma unroll
    for(int nt=0; nt<4; ++nt){
      const int col = n0 + wn*64 + nt*16 + lm;      // d
      const float bias = bv[col];
      ushort_t* vrow = Cout + ((size_t)bb*AA + col)*FF;
#pragma unroll
      for(int mt=0; mt<4; ++mt){
        const int f0 = mt*16 + lk*4;
        uint2 u;
        u.x = (unsigned)f2b(acc[mt][nt][0] + bias) | ((unsigned)f2b(acc[mt][nt][1] + bias) << 16);
        u.y = (unsigned)f2b(acc[mt][nt][2] + bias) | ((unsigned)f2b(acc[mt][nt][3] + bias) << 16);
        *(uint2*)(vrow + f0) = u;
      }
    }
  } else {
    // Q,K: bf16 row-major store
#pragma unroll
    for(int nt=0; nt<4; ++nt){
      const int col = n0 + wn*64 + nt*16 + lm;
#pragma unroll
      for(int mt=0; mt<4; ++mt){
#pragma unroll
        for(int reg=0; reg<4; ++reg){
          const int row = m0 + wm*64 + mt*16 + lk*4 + reg;
          Cout[(size_t)row*AA + col] = f2b(acc[mt][nt][reg]);
        }
      }
    }
  }
}

// ---------------------------------------------------------------------------
// Kernel 2: per-batch attention. grid 2048, block 256 (4 waves, 2 heads each)
// S = Q@K^T - u[k];  P = softmax_k(S);  out = P@V + Vsum + query, relu
// V arrives TRANSPOSED: Vt[b][d][f]
// ---------------------------------------------------------------------------
__global__ __launch_bounds__(256) void attn(const ushort_t* __restrict__ Qws,
                                            const ushort_t* __restrict__ Kws,
                                            const ushort_t* __restrict__ Vt,
                                            const float* __restrict__ query,
                                            float* __restrict__ out){
  const int b = blockIdx.x;
  const int t = threadIdx.x;
  __shared__ float mu[DD];
  __shared__ float vsum[DD];
  __shared__ float uu[HH][FF];
  __shared__ __align__(16) ushort_t P[4][64][72];

  const ushort_t* Qb = Qws + (size_t)b*FF*AA;
  const ushort_t* Kb = Kws + (size_t)b*FF*AA;
  const ushort_t* Vb = Vt  + (size_t)b*AA*FF;   // [d][f]

  // column means of Q (for centering)
  {
    float s0=0.f, s1=0.f;
#pragma unroll 8
    for(int f=0; f<FF; ++f){
      const ushort_t* qr = Qb + f*AA;
      s0 += b2f(qr[t]);     s1 += b2f(qr[t+256]);
    }
    mu[t]     = s0 * (1.f/64.f);
    mu[t+256] = s1 * (1.f/64.f);
  }
  // column sums of V == row sums of Vt (vectorized contiguous reads)
  {
#pragma unroll
    for(int it=0; it<2; ++it){
      const int d = t + it*256;
      const ushort_t* vr = Vb + (size_t)d*FF;
      float a = 0.f;
#pragma unroll
      for(int c=0; c<8; ++c){
        union { uint4 u; ushort_t s[8]; } w;
        w.u = *(const uint4*)(vr + c*8);
#pragma unroll
        for(int j=0; j<8; ++j) a += b2f(w.s[j]);
      }
      vsum[d] = a;
    }
  }
  __syncthreads();

  // u[h][k] = mu_h . K_h[k]
#pragma unroll
  for(int it=0; it<2; ++it){
    int idx = t + it*256;
    int h = idx >> 6, kk = idx & 63;
    const ushort_t* Kr = Kb + kk*AA + h*HD;
    float a = 0.f;
#pragma unroll
    for(int c=0; c<8; ++c){
      union { uint4 u; ushort_t s[8]; } w;
      w.u = *(const uint4*)(Kr + c*8);
#pragma unroll
      for(int j=0; j<8; ++j) a += mu[h*HD + c*8 + j] * b2f(w.s[j]);
    }
    uu[h][kk] = a;
  }
  __syncthreads();

  const int wave = t >> 6, lane = t & 63;
  const int lm = lane & 15, lk = lane >> 4;

  for(int hh=0; hh<2; ++hh){
    const int h = wave*2 + hh;

    // ---- scores S = Q_h @ K_h^T  (64x64, K-dim 64) ----
    f32x4_t acc[4][4];
#pragma unroll
    for(int a=0;a<4;++a)
#pragma unroll
      for(int bq=0;bq<4;++bq) acc[a][bq] = (f32x4_t){0.f,0.f,0.f,0.f};
#pragma unroll
    for(int ks=0; ks<2; ++ks){
      bf16x8_t af[4], bfv[4];
#pragma unroll
      for(int mt=0; mt<4; ++mt)
        af[mt]  = ld_frag(Qb + (size_t)(mt*16+lm)*AA + h*HD + ks*32 + lk*8);
#pragma unroll
      for(int nt=0; nt<4; ++nt)
        bfv[nt] = ld_frag(Kb + (size_t)(nt*16+lm)*AA + h*HD + ks*32 + lk*8);
#pragma unroll
      for(int mt=0; mt<4; ++mt)
#pragma unroll
        for(int nt=0; nt<4; ++nt)
          acc[mt][nt] = __builtin_amdgcn_mfma_f32_16x16x32_bf16(af[mt], bfv[nt], acc[mt][nt], 0, 0, 0);
    }

    // ---- subtract u, row softmax (row = mt*16+lk*4+reg; col = nt*16+lm) ----
    float uval[4];
#pragma unroll
    for(int nt=0; nt<4; ++nt) uval[nt] = uu[h][nt*16 + lm];

#pragma unroll
    for(int mt=0; mt<4; ++mt){
#pragma unroll
      for(int reg=0; reg<4; ++reg){
        float x0 = acc[mt][0][reg] - uval[0];
        float x1 = acc[mt][1][reg] - uval[1];
        float x2 = acc[mt][2][reg] - uval[2];
        float x3 = acc[mt][3][reg] - uval[3];
        float m = fmaxf(fmaxf(x0,x1), fmaxf(x2,x3));
        m = fmaxf(m, __shfl_xor(m, 1));
        m = fmaxf(m, __shfl_xor(m, 2));
        m = fmaxf(m, __shfl_xor(m, 4));
        m = fmaxf(m, __shfl_xor(m, 8));
        float e0 = __expf(x0-m), e1 = __expf(x1-m), e2 = __expf(x2-m), e3 = __expf(x3-m);
        float s = e0+e1+e2+e3;
        s += __shfl_xor(s, 1);
        s += __shfl_xor(s, 2);
        s += __shfl_xor(s, 4);
        s += __shfl_xor(s, 8);
        const float inv = 1.f / s;
        const int row = mt*16 + lk*4 + reg;
        P[wave][row][0*16 + lm] = f2b(e0*inv);
        P[wave][row][1*16 + lm] = f2b(e1*inv);
        P[wave][row][2*16 + lm] = f2b(e2*inv);
        P[wave][row][3*16 + lm] = f2b(e3*inv);
      }
    }

    // ---- out_h = P @ V_h  (64x64) ----
    f32x4_t acc2[4][4];
#pragma unroll
    for(int a=0;a<4;++a)
#pragma unroll
      for(int bq=0;bq<4;++bq) acc2[a][bq] = (f32x4_t){0.f,0.f,0.f,0.f};
#pragma unroll
    for(int ks=0; ks<2; ++ks){
      bf16x8_t pf[4], vf[4];
#pragma unroll
      for(int mt=0; mt<4; ++mt)
        pf[mt] = ld_frag(&P[wave][mt*16 + lm][ks*32 + lk*8]);
#pragma unroll
      for(int nt=0; nt<4; ++nt)
        vf[nt] = ld_frag(Vb + (size_t)(h*HD + nt*16 + lm)*FF + ks*32 + lk*8);
#pragma unroll
      for(int mt=0; mt<4; ++mt)
#pragma unroll
        for(int nt=0; nt<4; ++nt)
          acc2[mt][nt] = __builtin_amdgcn_mfma_f32_16x16x32_bf16(pf[mt], vf[nt], acc2[mt][nt], 0, 0, 0);
    }

    // ---- epilogue: + Vsum + residual, relu, store f32 ----
#pragma unroll
    for(int mt=0; mt<4; ++mt){
#pragma unroll
      for(int nt=0; nt<4; ++nt){
        const int dd = h*HD + nt*16 + lm;
#pragma unroll
        for(int reg=0; reg<4; ++reg){
          const int qrow = mt*16 + lk*4 + reg;
          const size_t gi = ((size_t)b*FF + qrow)*DD + dd;
          float val = acc2[mt][nt][reg] + vsum[dd] + query[gi];
          out[gi] = fmaxf(val, 0.f);
        }
      }
    }
  }
}

// ---------------------------------------------------------------------------
extern "C" void kernel_launch(void* const* d_in, const int* in_sizes, int n_in,
                              void* d_out, int out_size, void* d_ws, size_t ws_size,
                              hipStream_t stream){
  const float* query = (const float*)d_in[0];
  const float* key   = (const float*)d_in[1];
  const float* value = (const float*)d_in[2];
  const float* Wq    = (const float*)d_in[3];
  const float* Wk    = (const float*)d_in[5];
  const float* Wv    = (const float*)d_in[7];
  const float* bv    = (const float*)d_in[8];
  // Wk2/bk2/bq/bk unused: unary softmax over size-1 axis == 1, and bq/bk are
  // softmax-invariant after centering.

  ushort_t* WT  = (ushort_t*)d_ws;                              // 3 x 512x512 bf16
  ushort_t* QKV = (ushort_t*)((char*)d_ws + (size_t)(1<<21));   // Q,K row-major + Vt
  float* out = (float*)d_out;

  prep_w<<<dim3(16,16,3), 256, 0, stream>>>(Wq, Wk, Wv, WT);
  gemm_qkv<<<12288, 256, 0, stream>>>(query, key, value, WT, bv, QKV);
  attn<<<2048, 256, 0, stream>>>(QKV,
                                 QKV + (size_t)MM*AA,
                                 QKV + 2*(size_t)MM*AA,
                                 query, out);
}